// Round 1
// baseline (1963.884 us; speedup 1.0000x reference)
//
#include <hip/hip_runtime.h>

#pragma clang fp contract(off)

#define ALPHA  0.9f
#define RHO    0.985f
#define BETA_A 1.8f
#define TH     1.0f

// ---------------------------------------------------------------------------
// Generic 32x32 tiled transpose: src[R][C] -> dst[C][R]
// ---------------------------------------------------------------------------
__global__ __launch_bounds__(256) void transpose_k(const float* __restrict__ src,
                                                   float* __restrict__ dst,
                                                   int R, int C) {
    __shared__ float tile[32][33];
    const int c0 = blockIdx.x * 32;
    const int r0 = blockIdx.y * 32;
    const int tx = threadIdx.x, ty = threadIdx.y;
#pragma unroll
    for (int i = 0; i < 4; ++i)
        tile[ty + i * 8][tx] = src[(r0 + ty + i * 8) * C + c0 + tx];
    __syncthreads();
#pragma unroll
    for (int i = 0; i < 4; ++i)
        dst[(c0 + ty + i * 8) * R + r0 + tx] = tile[tx][ty + i * 8];
}

// ---------------------------------------------------------------------------
// Input projection: out[r][n] = sum_k inp[r][k] * Wt[k][n] + bias[n]
// inp: [4096][512], Wt: first 512 rows of [*][1024], out: [4096][1024]
// block = 256 threads = 256 n's; each block does 16 rows.
// ---------------------------------------------------------------------------
__global__ __launch_bounds__(256) void ip_gemm(const float* __restrict__ inp,
                                               const float* __restrict__ Wt,
                                               const float* __restrict__ bias,
                                               float* __restrict__ out) {
    __shared__ __align__(16) float s_in[512 * 20];  // [k][r] padded to 20
    const int tid   = threadIdx.x;
    const int chunk = blockIdx.x;        // 0..3  (n chunk of 256)
    const int rbase = blockIdx.y * 16;   // 0..4095 rows, 16 per block

    for (int idx = tid; idx < 16 * 512; idx += 256) {
        const int r = idx >> 9, k = idx & 511;
        s_in[k * 20 + r] = inp[(rbase + r) * 512 + k];
    }
    __syncthreads();

    const int n = chunk * 256 + tid;
    float acc[16];
#pragma unroll
    for (int r = 0; r < 16; ++r) acc[r] = 0.f;

    for (int k = 0; k < 512; ++k) {
        const float w = Wt[k * 1024 + n];
        const float4* p = (const float4*)(s_in + k * 20);
        const float4 x0 = p[0], x1 = p[1], x2 = p[2], x3 = p[3];
        acc[0]  = fmaf(x0.x, w, acc[0]);  acc[1]  = fmaf(x0.y, w, acc[1]);
        acc[2]  = fmaf(x0.z, w, acc[2]);  acc[3]  = fmaf(x0.w, w, acc[3]);
        acc[4]  = fmaf(x1.x, w, acc[4]);  acc[5]  = fmaf(x1.y, w, acc[5]);
        acc[6]  = fmaf(x1.z, w, acc[6]);  acc[7]  = fmaf(x1.w, w, acc[7]);
        acc[8]  = fmaf(x2.x, w, acc[8]);  acc[9]  = fmaf(x2.y, w, acc[9]);
        acc[10] = fmaf(x2.z, w, acc[10]); acc[11] = fmaf(x2.w, w, acc[11]);
        acc[12] = fmaf(x3.x, w, acc[12]); acc[13] = fmaf(x3.y, w, acc[13]);
        acc[14] = fmaf(x3.z, w, acc[14]); acc[15] = fmaf(x3.w, w, acc[15]);
    }
    const float bn = bias[n];
#pragma unroll
    for (int r = 0; r < 16; ++r) out[(rbase + r) * 1024 + n] = acc[r] + bn;
}

// ---------------------------------------------------------------------------
// Main recurrent kernel: one block per batch row, thread = neuron index.
// ---------------------------------------------------------------------------
__device__ __forceinline__ int compact_idx(bool pred, int* list, int* wcnt,
                                           int n, int wid, int lane) {
    const unsigned long long m = __ballot(pred);
    if (lane == 0) wcnt[wid] = __popcll(m);
    __syncthreads();
    int base = 0, total = 0;
#pragma unroll
    for (int w = 0; w < 16; ++w) {
        const int c = wcnt[w];
        total += c;
        if (w < wid) base += c;
    }
    if (pred) list[base + __popcll(m & ((1ull << lane) - 1ull))] = n;
    __syncthreads();
    return total;
}

template <int S>
__device__ __forceinline__ float sp_accum(const float* __restrict__ W,
                                          const int* __restrict__ list,
                                          int cnt, int n) {
    float a0 = 0.f, a1 = 0.f, a2 = 0.f, a3 = 0.f;
    int i = 0;
    for (; i + 4 <= cnt; i += 4) {
        const int4 j = *(const int4*)(list + i);
        a0 += W[j.x * S + n];
        a1 += W[j.y * S + n];
        a2 += W[j.z * S + n];
        a3 += W[j.w * S + n];
    }
    for (; i < cnt; ++i) a0 += W[list[i] * S + n];
    return (a0 + a1) + (a2 + a3);
}

__global__ __launch_bounds__(1024, 4) void rsnn_main(
    const float* __restrict__ Wt_pre,   // [1536][1024]
    const float* __restrict__ Wt_ad,    // [1024][1024]
    const float* __restrict__ Wt_post,  // [1536][1024]
    const float* __restrict__ Wt_out,   // [1024][256]
    const float* __restrict__ IP_pre,   // [4096][1024]  (inp part + b_pre)
    const float* __restrict__ IP_post,  // [4096][1024]  (inp part + b_post)
    const float* __restrict__ b_ad_p,   // [1024]
    const float* __restrict__ b_out_p,  // [256]
    float* __restrict__ out)            // o [32][128][256] ++ spikes [128][1024]
{
    const int n    = threadIdx.x;
    const int b    = blockIdx.x;
    const int wid  = n >> 6;
    const int lane = n & 63;

    __shared__ __align__(16) int listA[1024];  // s_a indices
    __shared__ __align__(16) int listB[1024];  // s_pre indices
    __shared__ __align__(16) int listC[1024];  // s_post indices
    __shared__ int wcnt[16];

    float v_pre = 0.f, v_a = 0.f, ba = 0.f, v_post = 0.f;
    const float bad  = b_ad_p[n];
    const float bout = (n < 256) ? b_out_p[n] : 0.f;
    const float* WpreA  = Wt_pre  + 512 * 1024;
    const float* WpostA = Wt_post + 512 * 1024;

    int cntA = 0;  // spikes (s_a) start at zero
    bool sa = false;
    __syncthreads();

    for (int t = 0; t < 32; ++t) {
        const int row   = t * 128 + b;
        const float ipre  = IP_pre [row * 1024 + n];
        const float ipost = IP_post[row * 1024 + n];
        for (int k = 0; k < 3; ++k) {
            // ---- A: v_pre = a*v_pre + [inp,spikes]@W_pre.T + b_pre ----
            float acc = sp_accum<1024>(WpreA, listA, cntA, n);
            v_pre = ALPHA * v_pre + ipre + acc;
            float d = v_pre - TH;
            const bool sp = d > 0.f;
            if (sp) v_pre = d;
            const int cntB = compact_idx(sp, listB, wcnt, n, wid, lane);

            // ---- B: v_a = a*v_a + s_pre@W_ad.T + b_ad; adaptive thresh ----
            acc = sp_accum<1024>(Wt_ad, listB, cntB, n);
            v_a = ALPHA * v_a + acc + bad;
            const float th = TH + BETA_A * ba;
            d = v_a - th;
            sa = d > 0.f;
            if (sa) v_a = d;
            ba = RHO * ba + (sa ? 1.f : 0.f);
            cntA = compact_idx(sa, listA, wcnt, n, wid, lane);

            // ---- C: v_post = a*v_post + [inp,s_a]@W_post.T + b_post ----
            acc = sp_accum<1024>(WpostA, listA, cntA, n);
            v_post = ALPHA * v_post + ipost + acc;
            d = v_post - TH;
            const bool spost = d > 0.f;
            if (spost) v_post = d;

            if (k == 2) {
                const int cntC = compact_idx(spost, listC, wcnt, n, wid, lane);
                if (n < 256) {
                    const float o = sp_accum<256>(Wt_out, listC, cntC, n);
                    out[row * 256 + n] = o + bout;
                }
                if (t == 31)
                    out[32 * 128 * 256 + b * 1024 + n] = sa ? 1.f : 0.f;
            }
        }
    }
}

// ---------------------------------------------------------------------------
extern "C" void kernel_launch(void* const* d_in, const int* in_sizes, int n_in,
                              void* d_out, int out_size, void* d_ws, size_t ws_size,
                              hipStream_t stream) {
    (void)in_sizes; (void)n_in; (void)out_size; (void)ws_size;
    const float* inp    = (const float*)d_in[0];  // [32][128][512]
    const float* W_pre  = (const float*)d_in[1];  // [1024][1536]
    const float* b_pre  = (const float*)d_in[2];  // [1024]
    const float* W_ad   = (const float*)d_in[3];  // [1024][1024]
    const float* b_ad   = (const float*)d_in[4];  // [1024]
    const float* W_post = (const float*)d_in[5];  // [1024][1536]
    const float* b_post = (const float*)d_in[6];  // [1024]
    const float* W_out  = (const float*)d_in[7];  // [256][1024]
    const float* b_out  = (const float*)d_in[8];  // [256]

    float* ws      = (float*)d_ws;
    float* Wt_pre  = ws;                          // 1536*1024
    float* Wt_post = Wt_pre  + 1536 * 1024;       // 1536*1024
    float* Wt_ad   = Wt_post + 1536 * 1024;       // 1024*1024
    float* Wt_out  = Wt_ad   + 1024 * 1024;       // 1024*256
    float* IP_pre  = Wt_out  + 1024 * 256;        // 4096*1024
    float* IP_post = IP_pre  + 4096 * 1024;       // 4096*1024

    transpose_k<<<dim3(48, 32), dim3(32, 8), 0, stream>>>(W_pre,  Wt_pre,  1024, 1536);
    transpose_k<<<dim3(48, 32), dim3(32, 8), 0, stream>>>(W_post, Wt_post, 1024, 1536);
    transpose_k<<<dim3(32, 32), dim3(32, 8), 0, stream>>>(W_ad,   Wt_ad,   1024, 1024);
    transpose_k<<<dim3(32, 8),  dim3(32, 8), 0, stream>>>(W_out,  Wt_out,  256,  1024);

    ip_gemm<<<dim3(4, 256), 256, 0, stream>>>(inp, Wt_pre,  b_pre,  IP_pre);
    ip_gemm<<<dim3(4, 256), 256, 0, stream>>>(inp, Wt_post, b_post, IP_post);

    rsnn_main<<<128, 1024, 0, stream>>>(Wt_pre, Wt_ad, Wt_post, Wt_out,
                                        IP_pre, IP_post, b_ad, b_out,
                                        (float*)d_out);
}